// Round 12
// baseline (203.079 us; speedup 1.0000x reference)
//
#include <hip/hip_runtime.h>
#include <hip/hip_bf16.h>
#include <stdint.h>

// Problem constants: B=4, CIN=COUT=256, H=W=64, 3x3, pad=1, stride=1, dil=1
#define KDIM 2304   // CIN * 9, GEMM K

typedef __bf16 bf16_t;
typedef bf16_t bf16x8 __attribute__((ext_vector_type(8)));
typedef float f32x4 __attribute__((ext_vector_type(4)));
typedef float f32x2 __attribute__((ext_vector_type(2)));

__device__ __forceinline__ float b2f_lo(uint32_t u) {
  union { uint32_t i; float f; } c; c.i = u << 16; return c.f;
}
__device__ __forceinline__ float b2f_hi(uint32_t u) {
  union { uint32_t i; float f; } c; c.i = u & 0xffff0000u; return c.f;
}
__device__ __forceinline__ uint32_t pk_bf16(float a, float b) {
  __hip_bfloat162 h = __float22bfloat162_rn(make_float2(a, b));
  union { __hip_bfloat162 h; uint32_t u; } c; c.h = h; return c.u;
}

// blend 4 corners (8 ch each) -> packed bf16x8 (r0-verified math)
__device__ __forceinline__ uint4 blend8(const uint4 d[4], const float cw[4]) {
  f32x2 f0 = {0.f, 0.f}, f1 = {0.f, 0.f}, f2 = {0.f, 0.f}, f3 = {0.f, 0.f};
#pragma unroll
  for (int c = 0; c < 4; ++c) {
    f32x2 wc = {cw[c], cw[c]};
    f0 += wc * f32x2{b2f_lo(d[c].x), b2f_hi(d[c].x)};
    f1 += wc * f32x2{b2f_lo(d[c].y), b2f_hi(d[c].y)};
    f2 += wc * f32x2{b2f_lo(d[c].z), b2f_hi(d[c].z)};
    f3 += wc * f32x2{b2f_lo(d[c].w), b2f_hi(d[c].w)};
  }
  uint4 o;
  o.x = pk_bf16(f0.x, f0.y);
  o.y = pk_bf16(f1.x, f1.y);
  o.z = pk_bf16(f2.x, f2.y);
  o.w = pk_bf16(f3.x, f3.y);
  return o;
}

// ---------------- merged prep kernel (r10/r11-verified)
__global__ __launch_bounds__(256) void k_prep(const float* __restrict__ x,
                                              uint16_t* __restrict__ xt,
                                              const float* __restrict__ w,
                                              uint16_t* __restrict__ wt2) {
  int tid = threadIdx.x;
  if (blockIdx.x < 1024) {
    __shared__ float tile[64][65];
    int b = blockIdx.x >> 8;
    int cgrp = (blockIdx.x >> 6) & 3;
    int sgrp = blockIdx.x & 63;
    int c0 = cgrp << 6, s0 = sgrp << 6;
#pragma unroll
    for (int it = 0; it < 4; ++it) {
      int f = tid + it * 256;
      int rr = f >> 4, col = (f & 15) << 2;
      float4 v = *(const float4*)&x[((size_t)(b * 256 + c0 + rr)) * 4096 + s0 + col];
      tile[rr][col + 0] = v.x;
      tile[rr][col + 1] = v.y;
      tile[rr][col + 2] = v.z;
      tile[rr][col + 3] = v.w;
    }
    __syncthreads();
    int sp = tid >> 2, cb = (tid & 3) * 16;
    uint4 o1, o2;
    o1.x = pk_bf16(tile[cb + 0][sp], tile[cb + 1][sp]);
    o1.y = pk_bf16(tile[cb + 2][sp], tile[cb + 3][sp]);
    o1.z = pk_bf16(tile[cb + 4][sp], tile[cb + 5][sp]);
    o1.w = pk_bf16(tile[cb + 6][sp], tile[cb + 7][sp]);
    o2.x = pk_bf16(tile[cb + 8][sp], tile[cb + 9][sp]);
    o2.y = pk_bf16(tile[cb + 10][sp], tile[cb + 11][sp]);
    o2.z = pk_bf16(tile[cb + 12][sp], tile[cb + 13][sp]);
    o2.w = pk_bf16(tile[cb + 14][sp], tile[cb + 15][sp]);
    uint16_t* dst = &xt[((size_t)(b * 4096 + s0 + sp)) * 256 + c0 + cb];
    *(uint4*)dst = o1;
    *(uint4*)(dst + 8) = o2;
  } else {
    __shared__ float wl[2304];
    int row = blockIdx.x - 1024;
    const float* wrow = w + (size_t)row * KDIM;
    for (int i2 = tid; i2 < 2304; i2 += 256) wl[i2] = wrow[i2];
    __syncthreads();
    int strip = row >> 4, r16 = row & 15;
    for (int c = tid; c < 288; c += 256) {   // c = tap*32 + w64*8 + kh*4 + seg
      int tap = c >> 5, rem = c & 31;
      int w64 = rem >> 3, kh = (rem >> 2) & 1, seg = rem & 3;
      int i = tap * 4 + w64;
      int cin0 = w64 * 64 + kh * 32 + seg * 8;
      int lanex = seg * 16 + r16;
      uint16_t* dst = wt2 + (size_t)i * 16384 + (size_t)(strip * 128 + kh * 64 + lanex) * 8;
      uint4 o;
      o.x = pk_bf16(wl[(cin0 + 0) * 9 + tap], wl[(cin0 + 1) * 9 + tap]);
      o.y = pk_bf16(wl[(cin0 + 2) * 9 + tap], wl[(cin0 + 3) * 9 + tap]);
      o.z = pk_bf16(wl[(cin0 + 4) * 9 + tap], wl[(cin0 + 5) * 9 + tap]);
      o.w = pk_bf16(wl[(cin0 + 6) * 9 + tap], wl[(cin0 + 7) * 9 + tap]);
      *(uint4*)dst = o;
    }
  }
}

// per-thread bilinear corner setup for one tap (full 64-position row, wo = p)
__device__ __forceinline__ void mk_corners(int tap, int p, int ho,
                                           const float* s_off, const float* s_msk,
                                           float cw[4], int cpo[4]) {
  int kh = tap / 3, kw = tap - kh * 3;
  float dy = s_off[(2 * tap) * 64 + p];
  float dx = s_off[(2 * tap + 1) * 64 + p];
  float mm = s_msk[tap * 64 + p];
  float sy = (float)(ho - 1 + kh) + dy;
  float sx = (float)(p - 1 + kw) + dx;
  float fy = floorf(sy), fx = floorf(sx);
  int y0 = (int)fy, x0 = (int)fx;
  float wy = sy - fy, wx = sx - fx;
#pragma unroll
  for (int cy = 0; cy < 2; ++cy) {
#pragma unroll
    for (int cx = 0; cx < 2; ++cx) {
      int y = y0 + cy, xx = x0 + cx;
      float wgt = (cy ? wy : 1.f - wy) * (cx ? wx : 1.f - wx) * mm;
      bool v = ((unsigned)y < 64u) && ((unsigned)xx < 64u);
      wgt = v ? wgt : 0.f;
      int yc = min(max(y, 0), 63), xc = min(max(xx, 0), 63);
      cw[cy * 2 + cx] = wgt;
      cpo[cy * 2 + cx] = ((yc << 6) + xc) * 256;
    }
  }
}

// ---------------- FUSED: BK=256, 9 bodies, INTRA-BODY PIPELINE (distance-1)
// Block: 1024 thr = 16 waves (4/SIMD), grid 256 = 1 block/CU. BM=256, BN=64.
// r11 left ~4x350cy/body of exposed A(L2)/B(LDS) load latency: the r10 spill
// fence made each phase load-then-consume. This round: phase S's block issues
// A(S+1)+B(S+1) BEFORE MFMA(S) (registers double-set X/Y, U/V); phase 3
// preloads next body's A(0) (B(0) stays behind the barrier -> one ds_read
// latency per body by design). dnv gathers staggered (dnvA top, dnvB after
// phase 0); blends sit in the phase-1/2 gaps, >=2 phases after their gather.
// sched_barrier(0) after each MFMA cluster kept (r10 spill fence). Per-acc
// MFMA order identical to r11 -> output bit-identical (absmax 0.0078125).
// Spill sentinel: WRITE_SIZE must stay exactly 16384 KB.
__global__ __launch_bounds__(1024, 4) void k_fused(const uint16_t* __restrict__ xt,
                                                   const uint16_t* __restrict__ wt2,
                                                   const float* __restrict__ off,
                                                   const float* __restrict__ msk,
                                                   const float* __restrict__ bias,
                                                   float* __restrict__ out) {
  constexpr int ROWU = 272;            // 256 + 16 u16 pad -> 544 B row stride
  constexpr int BUFU = 64 * ROWU;
  __shared__ __align__(16) uint16_t Bs[2 * BUFU];   // 69632 B
  __shared__ float s_off[18 * 64];
  __shared__ float s_msk[9 * 64];

  int tid = threadIdx.x;
  int swz = ((int)blockIdx.x & 7) * 32 + ((int)blockIdx.x >> 3);
  int b = swz >> 6, ho = swz & 63;

  const float* offb = off + (size_t)b * 18 * 4096 + ho * 64;
  for (int i = tid; i < 18 * 64; i += 1024)
    s_off[i] = offb[(size_t)(i >> 6) * 4096 + (i & 63)];
  const float* mskb = msk + (size_t)b * 9 * 4096 + ho * 64;
  for (int i = tid; i < 9 * 64; i += 1024)
    s_msk[i] = mskb[(size_t)(i >> 6) * 4096 + (i & 63)];

  int lane = tid & 63, wv = tid >> 6;
  int wm = wv >> 1, wn = wv & 1;            // 8 M-tiles x 2 N-tiles of 32x32
  int q = lane >> 4, r = lane & 15;
  int p = tid >> 4, cg16 = tid & 15;
  int sA = cg16 >> 3, cg = cg16 & 7;
  const uint16_t* xtb = xt + (size_t)b * 1048576 + cg * 8;
  int chwA = sA * 64, chwB = chwA + 128;
  int ch = cg ^ (p & 7);
  int wcolA = p * ROWU + sA * 64 + ch * 8;
  int wcolB = wcolA + 128;

  f32x4 acc[2][2];
#pragma unroll
  for (int mi = 0; mi < 2; ++mi)
#pragma unroll
    for (int ni = 0; ni < 2; ++ni) acc[mi][ni] = f32x4{0.f, 0.f, 0.f, 0.f};

  __syncthreads();  // off/msk staged

  float cw[4];
  int cpo[4];
  uint4 dnvA[4], dnvB[4];
  uint4 oA, oB;
  bf16x8 X00, X01, X10, X11, Y00, Y01, Y10, Y11;       // A double-set
  bf16x8 U0k0, U0k1, U1k0, U1k1, V0k0, V0k1, V1k0, V1k1;  // B double-set

  int c0 = (q ^ (r & 7)) << 3;
  int c1 = c0 ^ 32;
  int rowb0 = (wn * 32 + r) * ROWU;

#define LOAD_A(P, BASE)                                                         \
  P##00 = *(const bf16x8*)(BASE);                                               \
  P##01 = *(const bf16x8*)((BASE) + 512);                                       \
  P##10 = *(const bf16x8*)((BASE) + 1024);                                      \
  P##11 = *(const bf16x8*)((BASE) + 1536);
#define LOAD_B(P, OFS)                                                          \
  P##0k0 = *(const bf16x8*)(bsrow + rowb0 + (OFS) + c0);                        \
  P##0k1 = *(const bf16x8*)(bsrow + rowb0 + (OFS) + c1);                        \
  P##1k0 = *(const bf16x8*)(bsrow + rowb0 + 16 * ROWU + (OFS) + c0);            \
  P##1k1 = *(const bf16x8*)(bsrow + rowb0 + 16 * ROWU + (OFS) + c1);
#define MFMA8(A, B)                                                             \
  __builtin_amdgcn_s_setprio(1);                                                \
  acc[0][0] = __builtin_amdgcn_mfma_f32_16x16x32_bf16(A##00, B##0k0, acc[0][0], 0, 0, 0); \
  acc[0][1] = __builtin_amdgcn_mfma_f32_16x16x32_bf16(A##00, B##1k0, acc[0][1], 0, 0, 0); \
  acc[1][0] = __builtin_amdgcn_mfma_f32_16x16x32_bf16(A##10, B##0k0, acc[1][0], 0, 0, 0); \
  acc[1][1] = __builtin_amdgcn_mfma_f32_16x16x32_bf16(A##10, B##1k0, acc[1][1], 0, 0, 0); \
  acc[0][0] = __builtin_amdgcn_mfma_f32_16x16x32_bf16(A##01, B##0k1, acc[0][0], 0, 0, 0); \
  acc[0][1] = __builtin_amdgcn_mfma_f32_16x16x32_bf16(A##01, B##1k1, acc[0][1], 0, 0, 0); \
  acc[1][0] = __builtin_amdgcn_mfma_f32_16x16x32_bf16(A##11, B##0k1, acc[1][0], 0, 0, 0); \
  acc[1][1] = __builtin_amdgcn_mfma_f32_16x16x32_bf16(A##11, B##1k1, acc[1][1], 0, 0, 0); \
  __builtin_amdgcn_s_setprio(0);

  // ---- prologue: corners(tap0); gather both chunks; blend -> Bs[0]; A(0,0)->X
  mk_corners(0, p, ho, s_off, s_msk, cw, cpo);
#pragma unroll
  for (int c = 0; c < 4; ++c) dnvA[c] = *(const uint4*)(xtb + cpo[c] + chwA);
#pragma unroll
  for (int c = 0; c < 4; ++c) dnvB[c] = *(const uint4*)(xtb + cpo[c] + chwB);
  {
    const uint16_t* wp0 = wt2 + wm * 2048 + lane * 8;
    LOAD_A(X, wp0)
  }
  *(uint4*)(Bs + wcolA) = blend8(dnvA, cw);
  *(uint4*)(Bs + wcolB) = blend8(dnvB, cw);
  __syncthreads();

#pragma unroll 1
  for (int i = 0; i < 9; ++i) {
    const uint16_t* wpb = wt2 + (size_t)(4 * i) * 16384 + wm * 2048 + lane * 8;
    const uint16_t* bsrow = Bs + (i & 1) * BUFU;
    bool more = (i < 8);
    // ---- stage 0: B(0) ds_read; next-tap corners + dnvA gather; A(1)/B(1)
    LOAD_B(U, 0)
    if (more) {
      mk_corners(i + 1, p, ho, s_off, s_msk, cw, cpo);
#pragma unroll
      for (int c = 0; c < 4; ++c) dnvA[c] = *(const uint4*)(xtb + cpo[c] + chwA);
    }
    LOAD_A(Y, wpb + 16384)
    LOAD_B(V, 64)
    MFMA8(X, U)                       // phase 0: A(0)*B(0)
    __builtin_amdgcn_sched_barrier(0);
    if (more) {
#pragma unroll
      for (int c = 0; c < 4; ++c) dnvB[c] = *(const uint4*)(xtb + cpo[c] + chwB);
    }
    LOAD_A(X, wpb + 2 * 16384)
    LOAD_B(U, 2 * 64)
    MFMA8(Y, V)                       // phase 1: A(1)*B(1)
    __builtin_amdgcn_sched_barrier(0);
    if (more) oA = blend8(dnvA, cw);
    LOAD_A(Y, wpb + 3 * 16384)
    LOAD_B(V, 3 * 64)
    MFMA8(X, U)                       // phase 2: A(2)*B(2)
    __builtin_amdgcn_sched_barrier(0);
    if (more) {
      oB = blend8(dnvB, cw);
      LOAD_A(X, wpb + 4 * 16384)      // next body's A(0)
    }
    MFMA8(Y, V)                       // phase 3: A(3)*B(3)
    if (more) {
      uint16_t* wdst = Bs + ((i + 1) & 1) * BUFU;
      *(uint4*)(wdst + wcolA) = oA;
      *(uint4*)(wdst + wcolB) = oB;
    }
    __syncthreads();
  }
#undef LOAD_A
#undef LOAD_B
#undef MFMA8

  // epilogue: C/D layout col(n) = lane&15 = r, row(m) = q*4 + j
#pragma unroll
  for (int mi = 0; mi < 2; ++mi) {
#pragma unroll
    for (int j = 0; j < 4; ++j) {
      int m = wm * 32 + mi * 16 + q * 4 + j;
      float bv = bias[m];
#pragma unroll
      for (int ni = 0; ni < 2; ++ni) {
        int wog = wn * 32 + ni * 16 + r;
        out[((size_t)(b * 256 + m)) * 4096 + ho * 64 + wog] = acc[mi][ni][j] + bv;
      }
    }
  }
}

extern "C" void kernel_launch(void* const* d_in, const int* in_sizes, int n_in,
                              void* d_out, int out_size, void* d_ws, size_t ws_size,
                              hipStream_t stream) {
  (void)in_sizes; (void)n_in; (void)out_size; (void)ws_size;
  const float* x      = (const float*)d_in[0];  // [4][256][64][64]
  const float* offset = (const float*)d_in[1];  // [4][18][64][64]
  const float* mask   = (const float*)d_in[2];  // [4][9][64][64]
  const float* weight = (const float*)d_in[3];  // [256][256][3][3]
  const float* bias   = (const float*)d_in[4];  // [256]
  float* out = (float*)d_out;                   // [4][256][64][64]

  uint8_t* ws = (uint8_t*)d_ws;
  uint16_t* xt  = (uint16_t*)ws;                // 8,388,608 B : NHWC bf16
  uint16_t* wt2 = (uint16_t*)(ws + 8388608);    // 1,179,648 B : fragment-linear

  k_prep<<<dim3(1280), 256, 0, stream>>>(x, xt, weight, wt2);
  k_fused<<<dim3(256), 1024, 0, stream>>>(xt, wt2, offset, mask, bias, out);
}